// Round 11
// baseline (133.374 us; speedup 1.0000x reference)
//
#include <hip/hip_runtime.h>
#include <hip/hip_bf16.h>
#include <math.h>

#define B 8
#define HH 28
#define WDIM 28
#define PIX 784
#define PPIX 900          // 30*30 padded
#define M_TOT 6272        // 49*128 exactly
#define NK 9
#define C1 256
#define HID 1024
#define OUT2 256
#define K1 (C1*9)    // 2304
#define NY 2560      // 9*256 deform cols + 243 pconv cols + 13 zero
#define KSP1 12      // pconv1 K-split

typedef short short8_t __attribute__((ext_vector_type(8)));
typedef unsigned short us8 __attribute__((ext_vector_type(8)));
typedef unsigned short us4 __attribute__((ext_vector_type(4)));
typedef float f32x4 __attribute__((ext_vector_type(4)));

__device__ inline float bf2f(unsigned short u){ union{unsigned i; float f;} w; w.i=((unsigned)u)<<16; return w.f; }
__device__ inline unsigned short f2bf(float f){ union{float ff; unsigned i;} w; w.ff=f; unsigned u=w.i; return (unsigned short)((u + 0x7FFFu + ((u>>16)&1u))>>16); }

__device__ inline void gload16(const void* g, void* l) {
  __builtin_amdgcn_global_load_lds((const __attribute__((address_space(1))) void*)g,
                                   (__attribute__((address_space(3))) void*)l, 16, 0, 0);
}

// bijective XCD-chunked swizzle (m204)
__device__ inline int xcd_swz(int bid, int nwg) {
  int q = nwg >> 3, r = nwg & 7;
  int xcd = bid & 7, idx = bid >> 3;
  int base = (xcd < r) ? xcd * (q + 1) : r * (q + 1) + (xcd - r) * q;
  return base + idx;
}

// ---- ALL prep work in ONE launch (block-range partitioned) ---------------
// [0, 1856): ring zero for xclp/Y; [1856, 3456): x transpose; rest: weights
#define NRING (2 * B * 116)      // 1856
#define NXPOSE (25 * 8 * B)      // 1600
__global__ __launch_bounds__(256) void prep_all(
    const float* __restrict__ x,
    const float* __restrict__ wc1, const float* __restrict__ wp1,
    const float* __restrict__ wm1, const float* __restrict__ wc2,
    const float* __restrict__ wp2, const float* __restrict__ wm2,
    unsigned short* __restrict__ xclp, unsigned short* __restrict__ Y,
    unsigned short* __restrict__ wr1, unsigned short* __restrict__ wpr1,
    unsigned short* __restrict__ wy2)
{
  __shared__ float lds[HID * 9];     // 36 KB (aliased by xpose tile)
  int bid = blockIdx.x;
  if (bid < NRING) {                 // ---- ring zero ----
    unsigned short* buf; int C;
    if (bid < B * 116) { buf = xclp; C = C1; }
    else               { buf = Y; C = NY; bid -= B * 116; }
    int r = bid % 116, b = bid / 116;
    int h, w;
    if (r < 30)      { h = 0;  w = r; }
    else if (r < 60) { h = 29; w = r - 30; }
    else if (r < 88) { h = r - 59; w = 0; }
    else             { h = r - 87; w = 29; }
    unsigned short* row = buf + ((size_t)b * PPIX + h * 30 + w) * C;
    for (int c = threadIdx.x * 8; c < C; c += 2048)
      *(us8*)(row + c) = us8{0,0,0,0,0,0,0,0};
    return;
  }
  bid -= NRING;
  if (bid < NXPOSE) {                // ---- x transpose -> padded CL bf16 ----
    unsigned short (*tile)[33] = (unsigned short (*)[33])lds;
    int p0 = (bid % 25) * 32, c0 = ((bid / 25) % 8) * 32, b = bid / 200;
    int tx = threadIdx.x & 31, ty = threadIdx.x >> 5;
    for (int i = ty; i < 32; i += 8) {
      int c = c0 + i, p = p0 + tx;
      unsigned short v = 0;
      if (p < PIX) v = f2bf(x[((size_t)b * C1 + c) * PIX + p]);
      tile[i][tx] = v;
    }
    __syncthreads();
    for (int i = ty; i < 32; i += 8) {
      int p = p0 + i, c = c0 + tx;
      if (p < PIX) {
        int h = p / WDIM, w = p % WDIM;
        xclp[((size_t)b * PPIX + (h + 1) * 30 + (w + 1)) * C1 + c] = tile[tx][i];
      }
    }
    return;
  }
  bid -= NXPOSE;
  if (bid < HID) {                   // ---- w_c1 repack ----
    for (int i = threadIdx.x; i < K1; i += 256) lds[i] = wc1[(size_t)bid * K1 + i];
    __syncthreads();
    for (int k = threadIdx.x; k < K1; k += 256) {
      int n = k >> 8, c = k & 255;
      wr1[(size_t)bid * K1 + k] = f2bf(lds[c * 9 + n]);
    }
    return;
  }
  if (bid < HID + 32) {              // ---- pconv1 weights ----
    int ch = bid - HID;
    const float* src = nullptr;
    if (ch < 18) src = wp1 + (size_t)ch * K1;
    else if (ch < 27) src = wm1 + (size_t)(ch - 18) * K1;
    for (int i = threadIdx.x; i < K1; i += 256) lds[i] = src ? src[i] : 0.f;
    __syncthreads();
    for (int k = threadIdx.x; k < K1; k += 256) {
      int n = k >> 8, c = k & 255;
      wpr1[(size_t)ch * K1 + k] = f2bf(lds[c * 9 + n]);
    }
    return;
  }
  bid -= HID + 32;                   // ---- layer-2 combined W (296) ----
  if (bid >= 283) {
    int j = 2547 + (bid - 283);
    for (int c = threadIdx.x; c < HID; c += 256) wy2[(size_t)j * HID + c] = 0;
    return;
  }
  const float* src;
  if (bid < 256) src = wc2 + (size_t)bid * HID * 9;
  else {
    int ch = bid - 256;
    src = (ch < 18) ? wp2 + (size_t)ch * HID * 9 : wm2 + (size_t)(ch - 18) * HID * 9;
  }
  for (int i = threadIdx.x; i < HID * 9; i += 256) lds[i] = src[i];
  __syncthreads();
  #pragma unroll
  for (int n = 0; n < 9; ++n) {
    int j = (bid < 256) ? n * 256 + bid : 2304 + n * 27 + (bid - 256);
    for (int c = threadIdx.x; c < HID; c += 256)
      wy2[(size_t)j * HID + c] = f2bf(lds[c * 9 + n]);
  }
}

// ------ pconv1 as skinny MFMA GEMM (2-phase dbuf): [M][9C] x [32][9C]^T ---
template<int C, int KSPLIT>
__global__ __launch_bounds__(256) void pconv_mfma(
    const unsigned short* __restrict__ xclp,
    const unsigned short* __restrict__ wpr,
    float* __restrict__ pmpart)              // [KSPLIT][M][32]
{
  __shared__ unsigned short As[2][128 * 64];
  __shared__ unsigned short Ws[2][32 * 64];
  const int K = 9 * C;
  int t = threadIdx.x, lane = t & 63, wv = t >> 6;
  int m0 = blockIdx.x * 128;
  int kz = blockIdx.y;
  int wm = (wv & 1) * 64, wo = (wv >> 1) * 16;
  f32x4 acc[4];
  #pragma unroll
  for (int i = 0; i < 4; ++i) acc[i] = {0.f, 0.f, 0.f, 0.f};
  long pbase[4];
  #pragma unroll
  for (int i = 0; i < 4; ++i) {
    int L = i * 256 + t, row = L >> 3;
    int m = m0 + row, b = m / PIX, pix = m - b * PIX;
    int h = pix / WDIM, w = pix - h * WDIM;
    pbase[i] = ((long)b * PPIX + (h + 1) * 30 + (w + 1)) * C;
  }
  auto stage = [&](int buf, int kk) {
    int n = kk / C, c0 = kk - n * C;
    long doff = (long)(((n / 3) - 1) * 30 + (n % 3) - 1) * C + c0;
    #pragma unroll
    for (int i = 0; i < 4; ++i) {
      int L = i * 256 + t, row = L >> 3, ch = L & 7;
      const char* src = (const char*)(xclp + pbase[i] + doff) + ((ch ^ (row & 7)) << 4);
      gload16(src, (char*)As[buf] + (size_t)(i * 256 + (wv << 6)) * 16);
    }
    {
      int row = t >> 3, ch = t & 7;
      const char* src = (const char*)(wpr + (size_t)row * K + kk) + ((ch ^ (row & 7)) << 4);
      gload16(src, (char*)Ws[buf] + (size_t)(wv << 6) * 16);
    }
  };

  int kbeg = kz * (K / KSPLIT), kend = kbeg + K / KSPLIT;
  stage(0, kbeg);
  asm volatile("s_waitcnt vmcnt(0)" ::: "memory");
  __syncthreads();
  int cur = 0;
  for (int k0 = kbeg; k0 < kend; k0 += 64, cur ^= 1) {
    if (k0 + 64 < kend) stage(cur ^ 1, k0 + 64);
    #pragma unroll
    for (int ks = 0; ks < 2; ++ks) {
      short8_t af[4], bq;
      {
        int row = wo + (lane & 15), ch = ks * 4 + (lane >> 4);
        bq = *(const short8_t*)((const char*)Ws[cur] + row * 128 + ((ch ^ (row & 7)) << 4));
      }
      #pragma unroll
      for (int fm = 0; fm < 4; ++fm) {
        int row = wm + fm * 16 + (lane & 15), ch = ks * 4 + (lane >> 4);
        af[fm] = *(const short8_t*)((const char*)As[cur] + row * 128 + ((ch ^ (row & 7)) << 4));
      }
      #pragma unroll
      for (int fm = 0; fm < 4; ++fm)
        acc[fm] = __builtin_amdgcn_mfma_f32_16x16x32_bf16(af[fm], bq, acc[fm], 0, 0, 0);
    }
    asm volatile("s_waitcnt vmcnt(0)" ::: "memory");
    __syncthreads();
  }
  float* dst = pmpart + (size_t)kz * M_TOT * 32;
  #pragma unroll
  for (int fm = 0; fm < 4; ++fm)
    #pragma unroll
    for (int r = 0; r < 4; ++r) {
      int ml = m0 + wm + fm * 16 + (lane >> 4) * 4 + r;
      int o = wo + (lane & 15);
      dst[(size_t)ml * 32 + o] = acc[fm][r];
    }
}

// ---- bilinear table tail: emit one (offsets, gains) entry ----------------
__device__ inline void mktab_emit(int m, int n, float ox, float oy, float om,
                                  const float* b_p, const float* b_m,
                                  int4* tabOff, float4* tabG)
{
  int bidx = m / PIX, pix = m % PIX;
  int hh = pix / WDIM, ww = pix % WDIM;
  float px = ox + b_p[n]     + (float)(hh + 1) + (float)(n / 3 - 1);
  float py = oy + b_p[9 + n] + (float)(ww + 1) + (float)(n % 3 - 1);
  float msk = 1.f / (1.f + expf(-(om + b_m[n])));
  float fx = floorf(px), fy = floorf(py);
  float qlx = fminf(fmaxf(fx, 0.f), 29.f);
  float qly = fminf(fmaxf(fy, 0.f), 29.f);
  float qrx = fminf(fmaxf(fx + 1.f, 0.f), 29.f);
  float qry = fminf(fmaxf(fy + 1.f, 0.f), 29.f);
  float pxc = fminf(fmaxf(px, 0.f), 29.f);
  float pyc = fminf(fmaxf(py, 0.f), 29.f);
  float glt = (1.f + (qlx - pxc)) * (1.f + (qly - pyc));
  float grb = (1.f - (qrx - pxc)) * (1.f - (qry - pyc));
  float glb = (1.f + (qlx - pxc)) * (1.f - (qry - pyc));
  float grt = (1.f - (qrx - pxc)) * (1.f + (qly - pyc));
  int ax = (int)qlx, ay = (int)qly, bx = (int)qrx, by = (int)qry;
  int pb = bidx * PPIX;
  *tabOff = make_int4(pb + ax * 30 + ay, pb + bx * 30 + by,
                      pb + ax * 30 + by, pb + bx * 30 + ay);
  *tabG   = make_float4(glt * msk, grb * msk, glb * msk, grt * msk);
}

// ---- sampler (layer 1) with FUSED mktab1: tab built in LDS, then gather --
template<int CIN, int KSPLIT>
__global__ __launch_bounds__(256) void sample_tab_kernel(
    const unsigned short* __restrict__ xclp,
    const float* __restrict__ pmpart,
    const float* __restrict__ b_p, const float* __restrict__ b_m,
    unsigned short* __restrict__ A)
{
  constexpr int LPM = CIN / 8;         // 32
  constexpr int MPB = 256 / LPM;       // 8
  __shared__ int4   stabO[MPB][NK];
  __shared__ float4 stabG[MPB][NK];
  int m0 = blockIdx.x * MPB;
  int t = threadIdx.x;
  if (t < MPB * NK) {
    int ml = t / NK, n = t % NK;
    int m = m0 + ml;
    float ox = 0.f, oy = 0.f, om = 0.f;
    #pragma unroll
    for (int kz = 0; kz < KSPLIT; ++kz) {
      const float* q = pmpart + (size_t)kz * M_TOT * 32 + (size_t)m * 32;
      ox += q[n]; oy += q[9 + n]; om += q[18 + n];
    }
    mktab_emit(m, n, ox, oy, om, b_p, b_m, &stabO[ml][n], &stabG[ml][n]);
  }
  __syncthreads();
  int mi = t / LPM;
  int c0 = (t % LPM) * 8;
  unsigned short* Arow = A + (size_t)(m0 + mi) * (NK * CIN);
  #pragma unroll
  for (int n = 0; n < NK; ++n) {
    int4 o = stabO[mi][n]; float4 g = stabG[mi][n];
    us8 a0 = *(const us8*)(xclp + (size_t)o.x * CIN + c0);
    us8 a1 = *(const us8*)(xclp + (size_t)o.y * CIN + c0);
    us8 a2 = *(const us8*)(xclp + (size_t)o.z * CIN + c0);
    us8 a3 = *(const us8*)(xclp + (size_t)o.w * CIN + c0);
    us8 r;
    #pragma unroll
    for (int j = 0; j < 8; ++j) {
      float v = g.x * bf2f(a0[j]) + g.y * bf2f(a1[j])
              + g.z * bf2f(a2[j]) + g.w * bf2f(a3[j]);
      r[j] = f2bf(v);
    }
    *(us8*)(Arow + n * CIN + c0) = r;
  }
}

// ------- MFMA GEMM: 2-slot COUNTED-vmcnt pipeline (T4), 128m x TN, 64KB ---
// Per k-step: vmcnt(8) -> barrier -> ds_read+MFMA -> barrier -> stage(t+2).
// Loads issued at iter t are waited at iter t+2 (one full iteration in
// flight). Raw s_barrier (NOT __syncthreads: that would re-insert vmcnt(0)).
// VAR=0: compact hcl [m][O] bf16 (+ReLU)
// VAR=3: padded-layout Y: row = b*900+(h+1)*30+(w+1), bf16
template<int TN, int VAR>
__global__ __launch_bounds__(256) void gemm_mfma(
    const unsigned short* __restrict__ A,
    const unsigned short* __restrict__ Wr,
    void* __restrict__ outv,
    int K, int O, int nOt, int nwg)
{
  __shared__ unsigned short As[2][128 * 64];
  __shared__ unsigned short Ws[2][TN * 64];
  constexpr int NFO = TN / 32;
  int t = threadIdx.x, lane = t & 63, wv = t >> 6;
  int swz = xcd_swz(blockIdx.x, nwg);
  int m0 = (swz / nOt) * 128, o0 = (swz % nOt) * TN;
  int wm = (wv & 1) * 64, wo = (wv >> 1) * (TN / 2);
  f32x4 acc[4][NFO];
  #pragma unroll
  for (int i = 0; i < 4; ++i)
    #pragma unroll
    for (int j = 0; j < NFO; ++j)
      acc[i][j] = {0.f, 0.f, 0.f, 0.f};

  auto stage = [&](int buf, int kk) {   // 4 + TN/32 = 8 VMEM ops/thread
    #pragma unroll
    for (int i = 0; i < 4; ++i) {
      int L = i * 256 + t, row = L >> 3, ch = L & 7;
      const char* src = (const char*)(A + (size_t)(m0 + row) * K + kk) + ((ch ^ (row & 7)) << 4);
      gload16(src, (char*)As[buf] + (size_t)(i * 256 + (wv << 6)) * 16);
    }
    #pragma unroll
    for (int i = 0; i < TN / 32; ++i) {
      int L = i * 256 + t, row = L >> 3, ch = L & 7;
      const char* src = (const char*)(Wr + (size_t)(o0 + row) * K + kk) + ((ch ^ (row & 7)) << 4);
      gload16(src, (char*)Ws[buf] + (size_t)(i * 256 + (wv << 6)) * 16);
    }
  };

  static_assert(TN == 128, "vmcnt literal assumes 8 loads/stage");
  int NT = K >> 6;
  stage(0, 0);
  stage(1, 64);
  for (int tt = 0; tt < NT; ++tt) {
    if (tt + 1 < NT) { asm volatile("s_waitcnt vmcnt(8)" ::: "memory"); }
    else             { asm volatile("s_waitcnt vmcnt(0)" ::: "memory"); }
    __builtin_amdgcn_s_barrier();    // all waves' loads for slot tt&1 landed
    int cur = tt & 1;
    #pragma unroll
    for (int ks = 0; ks < 2; ++ks) {
      short8_t af[4], bq[NFO];
      #pragma unroll
      for (int fm = 0; fm < 4; ++fm) {
        int row = wm + fm * 16 + (lane & 15), ch = ks * 4 + (lane >> 4);
        af[fm] = *(const short8_t*)((const char*)As[cur] + row * 128 + ((ch ^ (row & 7)) << 4));
      }
      #pragma unroll
      for (int fo = 0; fo < NFO; ++fo) {
        int row = wo + fo * 16 + (lane & 15), ch = ks * 4 + (lane >> 4);
        bq[fo] = *(const short8_t*)((const char*)Ws[cur] + row * 128 + ((ch ^ (row & 7)) << 4));
      }
      __builtin_amdgcn_s_setprio(1);
      #pragma unroll
      for (int fm = 0; fm < 4; ++fm)
        #pragma unroll
        for (int fo = 0; fo < NFO; ++fo)
          acc[fm][fo] = __builtin_amdgcn_mfma_f32_16x16x32_bf16(af[fm], bq[fo], acc[fm][fo], 0, 0, 0);
      __builtin_amdgcn_s_setprio(0);
    }
    __builtin_amdgcn_s_barrier();    // all waves consumed slot cur
    if (tt + 2 < NT) stage(cur, (tt + 2) << 6);
  }

  unsigned short* outp = (unsigned short*)outv;
  #pragma unroll
  for (int fm = 0; fm < 4; ++fm)
    #pragma unroll
    for (int r = 0; r < 4; ++r) {
      int m = m0 + wm + fm * 16 + (lane >> 4) * 4 + r;
      size_t base;
      if (VAR == 0) base = (size_t)m * O;
      else {
        int b = m / PIX, pix = m - b * PIX;
        int h = pix / WDIM, w = pix - h * WDIM;
        base = ((size_t)b * PPIX + (h + 1) * 30 + (w + 1)) * (size_t)O;
      }
      #pragma unroll
      for (int fo = 0; fo < NFO; ++fo) {
        int o = o0 + wo + fo * 16 + (lane & 15);
        float v = acc[fm][fo][r];
        if (VAR == 0) v = fmaxf(v, 0.f);
        outp[base + o] = f2bf(v);
      }
    }
}

// ---- deform epilogue with FUSED mktab2 (tab built in LDS from Y) ---------
__global__ __launch_bounds__(256) void depi2_kernel(
    const unsigned short* __restrict__ Y,  // [B*900][NY]
    const float* __restrict__ b_p, const float* __restrict__ b_m,
    float* __restrict__ out)               // [B][256][784]
{
  __shared__ int4   stabO[4][NK];
  __shared__ float4 stabG[4][NK];
  __shared__ float tile[256][4];
  int m0 = blockIdx.x * 4;
  int t = threadIdx.x;
  if (t < 4 * NK) {
    int g = t / NK, n = t % NK;
    int m = m0 + g;
    int b = m / PIX, pix = m % PIX;
    int h = pix / WDIM, w = pix % WDIM;
    int q0 = b * PPIX + (h + 1) * 30 + (w + 1);
    float ox = 0.f, oy = 0.f, om = 0.f;
    #pragma unroll
    for (int tap = 0; tap < NK; ++tap) {
      int q = q0 + (tap / 3 - 1) * 30 + (tap % 3 - 1);
      const unsigned short* base = Y + (size_t)q * NY + 2304 + tap * 27;
      ox += bf2f(base[n]); oy += bf2f(base[9 + n]); om += bf2f(base[18 + n]);
    }
    mktab_emit(m, n, ox, oy, om, b_p, b_m, &stabO[g][n], &stabG[g][n]);
  }
  __syncthreads();
  int b = m0 / PIX, pix0 = m0 % PIX;
  int g = t >> 6, lane = t & 63;
  f32x4 acc = {0.f, 0.f, 0.f, 0.f};
  #pragma unroll
  for (int n = 0; n < NK; ++n) {
    int4 o4 = stabO[g][n]; float4 g4 = stabG[g][n];
    int col = n * 256 + lane * 4;
    us4 y0 = *(const us4*)(Y + (size_t)o4.x * NY + col);
    us4 y1 = *(const us4*)(Y + (size_t)o4.y * NY + col);
    us4 y2 = *(const us4*)(Y + (size_t)o4.z * NY + col);
    us4 y3 = *(const us4*)(Y + (size_t)o4.w * NY + col);
    #pragma unroll
    for (int j = 0; j < 4; ++j)
      acc[j] += g4.x * bf2f(y0[j]) + g4.y * bf2f(y1[j])
              + g4.z * bf2f(y2[j]) + g4.w * bf2f(y3[j]);
  }
  #pragma unroll
  for (int j = 0; j < 4; ++j) tile[lane * 4 + j][g] = acc[j];
  __syncthreads();
  int o = t;
  float4 v = *(const float4*)&tile[o][0];
  *(float4*)&out[((size_t)b * OUT2 + o) * PIX + pix0] = v;
}

extern "C" void kernel_launch(void* const* d_in, const int* in_sizes, int n_in,
                              void* d_out, int out_size, void* d_ws, size_t ws_size,
                              hipStream_t stream)
{
  const float* x    = (const float*)d_in[0];
  const float* w_p1 = (const float*)d_in[1];
  const float* b_p1 = (const float*)d_in[2];
  const float* w_m1 = (const float*)d_in[3];
  const float* b_m1 = (const float*)d_in[4];
  const float* w_c1 = (const float*)d_in[5];
  const float* w_p2 = (const float*)d_in[6];
  const float* b_p2 = (const float*)d_in[7];
  const float* w_m2 = (const float*)d_in[8];
  const float* b_m2 = (const float*)d_in[9];
  const float* w_c2 = (const float*)d_in[10];
  float* out = (float*)d_out;

  char* ws = (char*)d_ws;
  auto align_up = [](size_t v) { return (v + 255) & ~(size_t)255; };
  size_t off = 0;
  unsigned short* xclp = (unsigned short*)(ws + off); off += align_up((size_t)B * PPIX * C1 * 2);
  unsigned short* hcl  = (unsigned short*)(ws + off); off += align_up((size_t)M_TOT * HID * 2);
  unsigned short* Y    = (unsigned short*)(ws + off); off += align_up((size_t)B * PPIX * NY * 2);
  float* pmpart = (float*)(ws + off); off += align_up((size_t)KSP1 * M_TOT * 32 * 4);
  unsigned short* wr1  = (unsigned short*)(ws + off); off += align_up((size_t)HID * K1 * 2);
  unsigned short* wy2  = (unsigned short*)(ws + off); off += align_up((size_t)NY * HID * 2);
  unsigned short* wpr1 = (unsigned short*)(ws + off); off += align_up((size_t)32 * K1 * 2);
  unsigned short* Abuf = (unsigned short*)(ws + off); off += align_up((size_t)M_TOT * K1 * 2);

  // all prep (ring zero + transpose + 3 weight repacks) in one launch
  prep_all<<<NRING + NXPOSE + HID + 32 + 296, 256, 0, stream>>>(
      x, w_c1, w_p1, w_m1, w_c2, w_p2, w_m2, xclp, Y, wr1, wpr1, wy2);

  // ---- layer 1 (materialized-A deformable GEMM) ----
  pconv_mfma<C1, KSP1><<<dim3(M_TOT / 128, KSP1), 256, 0, stream>>>(xclp, wpr1, pmpart);
  sample_tab_kernel<C1, KSP1><<<M_TOT / 8, 256, 0, stream>>>(
      xclp, pmpart, b_p1, b_m1, Abuf);
  {
    int nwg = (M_TOT / 128) * (HID / 128);   // 49*8 = 392
    gemm_mfma<128, 0><<<nwg, 256, 0, stream>>>(Abuf, wr1, hcl, K1, HID, HID / 128, nwg);
  }

  // ---- layer 2 (factorized: dense per-tap Y-GEMM + fused gather epilogue)
  {
    int nwg = (M_TOT / 128) * (NY / 128);    // 49*20 = 980
    gemm_mfma<128, 3><<<nwg, 256, 0, stream>>>(hcl, wy2, Y, HID, NY, NY / 128, nwg);
  }
  depi2_kernel<<<M_TOT / 4, 256, 0, stream>>>(Y, b_p2, b_m2, out);
}

// Round 12
// 125.060 us; speedup vs baseline: 1.0665x; 1.0665x over previous
//
#include <hip/hip_runtime.h>
#include <hip/hip_bf16.h>
#include <math.h>

#define B 8
#define HH 28
#define WDIM 28
#define PIX 784
#define PPIX 900          // 30*30 padded
#define M_TOT 6272        // 49*128 exactly
#define NK 9
#define C1 256
#define HID 1024
#define OUT2 256
#define K1 (C1*9)    // 2304
#define NY 2560      // 9*256 deform cols + 243 pconv cols + 13 zero
#define KSP1 12      // pconv1 K-split

typedef short short8_t __attribute__((ext_vector_type(8)));
typedef unsigned short us8 __attribute__((ext_vector_type(8)));
typedef unsigned short us4 __attribute__((ext_vector_type(4)));
typedef float f32x4 __attribute__((ext_vector_type(4)));

__device__ inline float bf2f(unsigned short u){ union{unsigned i; float f;} w; w.i=((unsigned)u)<<16; return w.f; }
__device__ inline unsigned short f2bf(float f){ union{float ff; unsigned i;} w; w.ff=f; unsigned u=w.i; return (unsigned short)((u + 0x7FFFu + ((u>>16)&1u))>>16); }

__device__ inline void gload16(const void* g, void* l) {
  __builtin_amdgcn_global_load_lds((const __attribute__((address_space(1))) void*)g,
                                   (__attribute__((address_space(3))) void*)l, 16, 0, 0);
}

// bijective XCD-chunked swizzle (m204)
__device__ inline int xcd_swz(int bid, int nwg) {
  int q = nwg >> 3, r = nwg & 7;
  int xcd = bid & 7, idx = bid >> 3;
  int base = (xcd < r) ? xcd * (q + 1) : r * (q + 1) + (xcd - r) * q;
  return base + idx;
}

// ---- ALL prep work in ONE launch (block-range partitioned) ---------------
// [0, 1856): ring zero for xclp/Y; [1856, 3456): x transpose; rest: weights
#define NRING (2 * B * 116)      // 1856
#define NXPOSE (25 * 8 * B)      // 1600
__global__ __launch_bounds__(256) void prep_all(
    const float* __restrict__ x,
    const float* __restrict__ wc1, const float* __restrict__ wp1,
    const float* __restrict__ wm1, const float* __restrict__ wc2,
    const float* __restrict__ wp2, const float* __restrict__ wm2,
    unsigned short* __restrict__ xclp, unsigned short* __restrict__ Y,
    unsigned short* __restrict__ wr1, unsigned short* __restrict__ wpr1,
    unsigned short* __restrict__ wy2)
{
  __shared__ float lds[HID * 9];     // 36 KB (aliased by xpose tile)
  int bid = blockIdx.x;
  if (bid < NRING) {                 // ---- ring zero ----
    unsigned short* buf; int C;
    if (bid < B * 116) { buf = xclp; C = C1; }
    else               { buf = Y; C = NY; bid -= B * 116; }
    int r = bid % 116, b = bid / 116;
    int h, w;
    if (r < 30)      { h = 0;  w = r; }
    else if (r < 60) { h = 29; w = r - 30; }
    else if (r < 88) { h = r - 59; w = 0; }
    else             { h = r - 87; w = 29; }
    unsigned short* row = buf + ((size_t)b * PPIX + h * 30 + w) * C;
    for (int c = threadIdx.x * 8; c < C; c += 2048)
      *(us8*)(row + c) = us8{0,0,0,0,0,0,0,0};
    return;
  }
  bid -= NRING;
  if (bid < NXPOSE) {                // ---- x transpose -> padded CL bf16 ----
    unsigned short (*tile)[33] = (unsigned short (*)[33])lds;
    int p0 = (bid % 25) * 32, c0 = ((bid / 25) % 8) * 32, b = bid / 200;
    int tx = threadIdx.x & 31, ty = threadIdx.x >> 5;
    for (int i = ty; i < 32; i += 8) {
      int c = c0 + i, p = p0 + tx;
      unsigned short v = 0;
      if (p < PIX) v = f2bf(x[((size_t)b * C1 + c) * PIX + p]);
      tile[i][tx] = v;
    }
    __syncthreads();
    for (int i = ty; i < 32; i += 8) {
      int p = p0 + i, c = c0 + tx;
      if (p < PIX) {
        int h = p / WDIM, w = p % WDIM;
        xclp[((size_t)b * PPIX + (h + 1) * 30 + (w + 1)) * C1 + c] = tile[tx][i];
      }
    }
    return;
  }
  bid -= NXPOSE;
  if (bid < HID) {                   // ---- w_c1 repack ----
    for (int i = threadIdx.x; i < K1; i += 256) lds[i] = wc1[(size_t)bid * K1 + i];
    __syncthreads();
    for (int k = threadIdx.x; k < K1; k += 256) {
      int n = k >> 8, c = k & 255;
      wr1[(size_t)bid * K1 + k] = f2bf(lds[c * 9 + n]);
    }
    return;
  }
  if (bid < HID + 32) {              // ---- pconv1 weights ----
    int ch = bid - HID;
    const float* src = nullptr;
    if (ch < 18) src = wp1 + (size_t)ch * K1;
    else if (ch < 27) src = wm1 + (size_t)(ch - 18) * K1;
    for (int i = threadIdx.x; i < K1; i += 256) lds[i] = src ? src[i] : 0.f;
    __syncthreads();
    for (int k = threadIdx.x; k < K1; k += 256) {
      int n = k >> 8, c = k & 255;
      wpr1[(size_t)ch * K1 + k] = f2bf(lds[c * 9 + n]);
    }
    return;
  }
  bid -= HID + 32;                   // ---- layer-2 combined W (296) ----
  if (bid >= 283) {
    int j = 2547 + (bid - 283);
    for (int c = threadIdx.x; c < HID; c += 256) wy2[(size_t)j * HID + c] = 0;
    return;
  }
  const float* src;
  if (bid < 256) src = wc2 + (size_t)bid * HID * 9;
  else {
    int ch = bid - 256;
    src = (ch < 18) ? wp2 + (size_t)ch * HID * 9 : wm2 + (size_t)(ch - 18) * HID * 9;
  }
  for (int i = threadIdx.x; i < HID * 9; i += 256) lds[i] = src[i];
  __syncthreads();
  #pragma unroll
  for (int n = 0; n < 9; ++n) {
    int j = (bid < 256) ? n * 256 + bid : 2304 + n * 27 + (bid - 256);
    for (int c = threadIdx.x; c < HID; c += 256)
      wy2[(size_t)j * HID + c] = f2bf(lds[c * 9 + n]);
  }
}

// ------ pconv1 as skinny MFMA GEMM (2-phase dbuf): [M][9C] x [32][9C]^T ---
template<int C, int KSPLIT>
__global__ __launch_bounds__(256) void pconv_mfma(
    const unsigned short* __restrict__ xclp,
    const unsigned short* __restrict__ wpr,
    float* __restrict__ pmpart)              // [KSPLIT][M][32]
{
  __shared__ unsigned short As[2][128 * 64];
  __shared__ unsigned short Ws[2][32 * 64];
  const int K = 9 * C;
  int t = threadIdx.x, lane = t & 63, wv = t >> 6;
  int m0 = blockIdx.x * 128;
  int kz = blockIdx.y;
  int wm = (wv & 1) * 64, wo = (wv >> 1) * 16;
  f32x4 acc[4];
  #pragma unroll
  for (int i = 0; i < 4; ++i) acc[i] = {0.f, 0.f, 0.f, 0.f};
  long pbase[4];
  #pragma unroll
  for (int i = 0; i < 4; ++i) {
    int L = i * 256 + t, row = L >> 3;
    int m = m0 + row, b = m / PIX, pix = m - b * PIX;
    int h = pix / WDIM, w = pix - h * WDIM;
    pbase[i] = ((long)b * PPIX + (h + 1) * 30 + (w + 1)) * C;
  }
  auto stage = [&](int buf, int kk) {
    int n = kk / C, c0 = kk - n * C;
    long doff = (long)(((n / 3) - 1) * 30 + (n % 3) - 1) * C + c0;
    #pragma unroll
    for (int i = 0; i < 4; ++i) {
      int L = i * 256 + t, row = L >> 3, ch = L & 7;
      const char* src = (const char*)(xclp + pbase[i] + doff) + ((ch ^ (row & 7)) << 4);
      gload16(src, (char*)As[buf] + (size_t)(i * 256 + (wv << 6)) * 16);
    }
    {
      int row = t >> 3, ch = t & 7;
      const char* src = (const char*)(wpr + (size_t)row * K + kk) + ((ch ^ (row & 7)) << 4);
      gload16(src, (char*)Ws[buf] + (size_t)(wv << 6) * 16);
    }
  };

  int kbeg = kz * (K / KSPLIT), kend = kbeg + K / KSPLIT;
  stage(0, kbeg);
  asm volatile("s_waitcnt vmcnt(0)" ::: "memory");
  __syncthreads();
  int cur = 0;
  for (int k0 = kbeg; k0 < kend; k0 += 64, cur ^= 1) {
    if (k0 + 64 < kend) stage(cur ^ 1, k0 + 64);
    #pragma unroll
    for (int ks = 0; ks < 2; ++ks) {
      short8_t af[4], bq;
      {
        int row = wo + (lane & 15), ch = ks * 4 + (lane >> 4);
        bq = *(const short8_t*)((const char*)Ws[cur] + row * 128 + ((ch ^ (row & 7)) << 4));
      }
      #pragma unroll
      for (int fm = 0; fm < 4; ++fm) {
        int row = wm + fm * 16 + (lane & 15), ch = ks * 4 + (lane >> 4);
        af[fm] = *(const short8_t*)((const char*)As[cur] + row * 128 + ((ch ^ (row & 7)) << 4));
      }
      #pragma unroll
      for (int fm = 0; fm < 4; ++fm)
        acc[fm] = __builtin_amdgcn_mfma_f32_16x16x32_bf16(af[fm], bq, acc[fm], 0, 0, 0);
    }
    asm volatile("s_waitcnt vmcnt(0)" ::: "memory");
    __syncthreads();
  }
  float* dst = pmpart + (size_t)kz * M_TOT * 32;
  #pragma unroll
  for (int fm = 0; fm < 4; ++fm)
    #pragma unroll
    for (int r = 0; r < 4; ++r) {
      int ml = m0 + wm + fm * 16 + (lane >> 4) * 4 + r;
      int o = wo + (lane & 15);
      dst[(size_t)ml * 32 + o] = acc[fm][r];
    }
}

// ---- bilinear table tail: emit one (offsets, gains) entry ----------------
__device__ inline void mktab_emit(int m, int n, float ox, float oy, float om,
                                  const float* b_p, const float* b_m,
                                  int4* tabOff, float4* tabG)
{
  int bidx = m / PIX, pix = m % PIX;
  int hh = pix / WDIM, ww = pix % WDIM;
  float px = ox + b_p[n]     + (float)(hh + 1) + (float)(n / 3 - 1);
  float py = oy + b_p[9 + n] + (float)(ww + 1) + (float)(n % 3 - 1);
  float msk = 1.f / (1.f + expf(-(om + b_m[n])));
  float fx = floorf(px), fy = floorf(py);
  float qlx = fminf(fmaxf(fx, 0.f), 29.f);
  float qly = fminf(fmaxf(fy, 0.f), 29.f);
  float qrx = fminf(fmaxf(fx + 1.f, 0.f), 29.f);
  float qry = fminf(fmaxf(fy + 1.f, 0.f), 29.f);
  float pxc = fminf(fmaxf(px, 0.f), 29.f);
  float pyc = fminf(fmaxf(py, 0.f), 29.f);
  float glt = (1.f + (qlx - pxc)) * (1.f + (qly - pyc));
  float grb = (1.f - (qrx - pxc)) * (1.f - (qry - pyc));
  float glb = (1.f + (qlx - pxc)) * (1.f - (qry - pyc));
  float grt = (1.f - (qrx - pxc)) * (1.f + (qly - pyc));
  int ax = (int)qlx, ay = (int)qly, bx = (int)qrx, by = (int)qry;
  int pb = bidx * PPIX;
  *tabOff = make_int4(pb + ax * 30 + ay, pb + bx * 30 + by,
                      pb + ax * 30 + by, pb + bx * 30 + ay);
  *tabG   = make_float4(glt * msk, grb * msk, glb * msk, grt * msk);
}

// ---- sampler (layer 1) with FUSED mktab1: tab built in LDS, then gather --
template<int CIN, int KSPLIT>
__global__ __launch_bounds__(256) void sample_tab_kernel(
    const unsigned short* __restrict__ xclp,
    const float* __restrict__ pmpart,
    const float* __restrict__ b_p, const float* __restrict__ b_m,
    unsigned short* __restrict__ A)
{
  constexpr int LPM = CIN / 8;         // 32
  constexpr int MPB = 256 / LPM;       // 8
  __shared__ int4   stabO[MPB][NK];
  __shared__ float4 stabG[MPB][NK];
  int m0 = blockIdx.x * MPB;
  int t = threadIdx.x;
  if (t < MPB * NK) {
    int ml = t / NK, n = t % NK;
    int m = m0 + ml;
    float ox = 0.f, oy = 0.f, om = 0.f;
    #pragma unroll
    for (int kz = 0; kz < KSPLIT; ++kz) {
      const float* q = pmpart + (size_t)kz * M_TOT * 32 + (size_t)m * 32;
      ox += q[n]; oy += q[9 + n]; om += q[18 + n];
    }
    mktab_emit(m, n, ox, oy, om, b_p, b_m, &stabO[ml][n], &stabG[ml][n]);
  }
  __syncthreads();
  int mi = t / LPM;
  int c0 = (t % LPM) * 8;
  unsigned short* Arow = A + (size_t)(m0 + mi) * (NK * CIN);
  #pragma unroll
  for (int n = 0; n < NK; ++n) {
    int4 o = stabO[mi][n]; float4 g = stabG[mi][n];
    us8 a0 = *(const us8*)(xclp + (size_t)o.x * CIN + c0);
    us8 a1 = *(const us8*)(xclp + (size_t)o.y * CIN + c0);
    us8 a2 = *(const us8*)(xclp + (size_t)o.z * CIN + c0);
    us8 a3 = *(const us8*)(xclp + (size_t)o.w * CIN + c0);
    us8 r;
    #pragma unroll
    for (int j = 0; j < 8; ++j) {
      float v = g.x * bf2f(a0[j]) + g.y * bf2f(a1[j])
              + g.z * bf2f(a2[j]) + g.w * bf2f(a3[j]);
      r[j] = f2bf(v);
    }
    *(us8*)(Arow + n * CIN + c0) = r;
  }
}

// ------- MFMA GEMM (R9-proven: 2-phase dbuf, vmcnt(0)+syncthreads,
//         XCD-chunked 1D grid) -- FROZEN at the 41 us configuration --------
// VAR=0: compact hcl [m][O] bf16 (+ReLU)
// VAR=3: padded-layout Y: row = b*900+(h+1)*30+(w+1), bf16
template<int TN, int VAR>
__global__ __launch_bounds__(256) void gemm_mfma(
    const unsigned short* __restrict__ A,
    const unsigned short* __restrict__ Wr,
    void* __restrict__ outv,
    int K, int O, int nOt, int nwg)
{
  __shared__ unsigned short As[2][128 * 64];
  __shared__ unsigned short Ws[2][TN * 64];
  constexpr int NFO = TN / 32;
  int t = threadIdx.x, lane = t & 63, wv = t >> 6;
  int swz = xcd_swz(blockIdx.x, nwg);
  int m0 = (swz / nOt) * 128, o0 = (swz % nOt) * TN;
  int wm = (wv & 1) * 64, wo = (wv >> 1) * (TN / 2);
  f32x4 acc[4][NFO];
  #pragma unroll
  for (int i = 0; i < 4; ++i)
    #pragma unroll
    for (int j = 0; j < NFO; ++j)
      acc[i][j] = {0.f, 0.f, 0.f, 0.f};

  auto stage = [&](int buf, int kk) {
    #pragma unroll
    for (int i = 0; i < 4; ++i) {
      int L = i * 256 + t, row = L >> 3, ch = L & 7;
      const char* src = (const char*)(A + (size_t)(m0 + row) * K + kk) + ((ch ^ (row & 7)) << 4);
      gload16(src, (char*)As[buf] + (size_t)(i * 256 + (wv << 6)) * 16);
    }
    #pragma unroll
    for (int i = 0; i < TN / 32; ++i) {
      int L = i * 256 + t, row = L >> 3, ch = L & 7;
      const char* src = (const char*)(Wr + (size_t)(o0 + row) * K + kk) + ((ch ^ (row & 7)) << 4);
      gload16(src, (char*)Ws[buf] + (size_t)(i * 256 + (wv << 6)) * 16);
    }
  };

  stage(0, 0);
  asm volatile("s_waitcnt vmcnt(0)" ::: "memory");
  __syncthreads();
  int cur = 0;
  for (int k0 = 0; k0 < K; k0 += 64, cur ^= 1) {
    if (k0 + 64 < K) stage(cur ^ 1, k0 + 64);
    #pragma unroll
    for (int ks = 0; ks < 2; ++ks) {
      short8_t af[4], bq[NFO];
      #pragma unroll
      for (int fm = 0; fm < 4; ++fm) {
        int row = wm + fm * 16 + (lane & 15), ch = ks * 4 + (lane >> 4);
        af[fm] = *(const short8_t*)((const char*)As[cur] + row * 128 + ((ch ^ (row & 7)) << 4));
      }
      #pragma unroll
      for (int fo = 0; fo < NFO; ++fo) {
        int row = wo + fo * 16 + (lane & 15), ch = ks * 4 + (lane >> 4);
        bq[fo] = *(const short8_t*)((const char*)Ws[cur] + row * 128 + ((ch ^ (row & 7)) << 4));
      }
      #pragma unroll
      for (int fm = 0; fm < 4; ++fm)
        #pragma unroll
        for (int fo = 0; fo < NFO; ++fo)
          acc[fm][fo] = __builtin_amdgcn_mfma_f32_16x16x32_bf16(af[fm], bq[fo], acc[fm][fo], 0, 0, 0);
    }
    asm volatile("s_waitcnt vmcnt(0)" ::: "memory");
    __syncthreads();
  }

  unsigned short* outp = (unsigned short*)outv;
  #pragma unroll
  for (int fm = 0; fm < 4; ++fm)
    #pragma unroll
    for (int r = 0; r < 4; ++r) {
      int m = m0 + wm + fm * 16 + (lane >> 4) * 4 + r;
      size_t base;
      if (VAR == 0) base = (size_t)m * O;
      else {
        int b = m / PIX, pix = m - b * PIX;
        int h = pix / WDIM, w = pix - h * WDIM;
        base = ((size_t)b * PPIX + (h + 1) * 30 + (w + 1)) * (size_t)O;
      }
      #pragma unroll
      for (int fo = 0; fo < NFO; ++fo) {
        int o = o0 + wo + fo * 16 + (lane & 15);
        float v = acc[fm][fo][r];
        if (VAR == 0) v = fmaxf(v, 0.f);
        outp[base + o] = f2bf(v);
      }
    }
}

// ---- deform epilogue with FUSED mktab2 (tab built in LDS from Y) ---------
__global__ __launch_bounds__(256) void depi2_kernel(
    const unsigned short* __restrict__ Y,  // [B*900][NY]
    const float* __restrict__ b_p, const float* __restrict__ b_m,
    float* __restrict__ out)               // [B][256][784]
{
  __shared__ int4   stabO[4][NK];
  __shared__ float4 stabG[4][NK];
  __shared__ float tile[256][4];
  int m0 = blockIdx.x * 4;
  int t = threadIdx.x;
  if (t < 4 * NK) {
    int g = t / NK, n = t % NK;
    int m = m0 + g;
    int b = m / PIX, pix = m % PIX;
    int h = pix / WDIM, w = pix % WDIM;
    int q0 = b * PPIX + (h + 1) * 30 + (w + 1);
    float ox = 0.f, oy = 0.f, om = 0.f;
    #pragma unroll
    for (int tap = 0; tap < NK; ++tap) {
      int q = q0 + (tap / 3 - 1) * 30 + (tap % 3 - 1);
      const unsigned short* base = Y + (size_t)q * NY + 2304 + tap * 27;
      ox += bf2f(base[n]); oy += bf2f(base[9 + n]); om += bf2f(base[18 + n]);
    }
    mktab_emit(m, n, ox, oy, om, b_p, b_m, &stabO[g][n], &stabG[g][n]);
  }
  __syncthreads();
  int b = m0 / PIX, pix0 = m0 % PIX;
  int g = t >> 6, lane = t & 63;
  f32x4 acc = {0.f, 0.f, 0.f, 0.f};
  #pragma unroll
  for (int n = 0; n < NK; ++n) {
    int4 o4 = stabO[g][n]; float4 g4 = stabG[g][n];
    int col = n * 256 + lane * 4;
    us4 y0 = *(const us4*)(Y + (size_t)o4.x * NY + col);
    us4 y1 = *(const us4*)(Y + (size_t)o4.y * NY + col);
    us4 y2 = *(const us4*)(Y + (size_t)o4.z * NY + col);
    us4 y3 = *(const us4*)(Y + (size_t)o4.w * NY + col);
    #pragma unroll
    for (int j = 0; j < 4; ++j)
      acc[j] += g4.x * bf2f(y0[j]) + g4.y * bf2f(y1[j])
              + g4.z * bf2f(y2[j]) + g4.w * bf2f(y3[j]);
  }
  #pragma unroll
  for (int j = 0; j < 4; ++j) tile[lane * 4 + j][g] = acc[j];
  __syncthreads();
  int o = t;
  float4 v = *(const float4*)&tile[o][0];
  *(float4*)&out[((size_t)b * OUT2 + o) * PIX + pix0] = v;
}

extern "C" void kernel_launch(void* const* d_in, const int* in_sizes, int n_in,
                              void* d_out, int out_size, void* d_ws, size_t ws_size,
                              hipStream_t stream)
{
  const float* x    = (const float*)d_in[0];
  const float* w_p1 = (const float*)d_in[1];
  const float* b_p1 = (const float*)d_in[2];
  const float* w_m1 = (const float*)d_in[3];
  const float* b_m1 = (const float*)d_in[4];
  const float* w_c1 = (const float*)d_in[5];
  const float* w_p2 = (const float*)d_in[6];
  const float* b_p2 = (const float*)d_in[7];
  const float* w_m2 = (const float*)d_in[8];
  const float* b_m2 = (const float*)d_in[9];
  const float* w_c2 = (const float*)d_in[10];
  float* out = (float*)d_out;

  char* ws = (char*)d_ws;
  auto align_up = [](size_t v) { return (v + 255) & ~(size_t)255; };
  size_t off = 0;
  unsigned short* xclp = (unsigned short*)(ws + off); off += align_up((size_t)B * PPIX * C1 * 2);
  unsigned short* hcl  = (unsigned short*)(ws + off); off += align_up((size_t)M_TOT * HID * 2);
  unsigned short* Y    = (unsigned short*)(ws + off); off += align_up((size_t)B * PPIX * NY * 2);
  float* pmpart = (float*)(ws + off); off += align_up((size_t)KSP1 * M_TOT * 32 * 4);
  unsigned short* wr1  = (unsigned short*)(ws + off); off += align_up((size_t)HID * K1 * 2);
  unsigned short* wy2  = (unsigned short*)(ws + off); off += align_up((size_t)NY * HID * 2);
  unsigned short* wpr1 = (unsigned short*)(ws + off); off += align_up((size_t)32 * K1 * 2);
  unsigned short* Abuf = (unsigned short*)(ws + off); off += align_up((size_t)M_TOT * K1 * 2);

  // all prep (ring zero + transpose + 3 weight repacks) in one launch
  prep_all<<<NRING + NXPOSE + HID + 32 + 296, 256, 0, stream>>>(
      x, w_c1, w_p1, w_m1, w_c2, w_p2, w_m2, xclp, Y, wr1, wpr1, wy2);

  // ---- layer 1 (materialized-A deformable GEMM) ----
  pconv_mfma<C1, KSP1><<<dim3(M_TOT / 128, KSP1), 256, 0, stream>>>(xclp, wpr1, pmpart);
  sample_tab_kernel<C1, KSP1><<<M_TOT / 8, 256, 0, stream>>>(
      xclp, pmpart, b_p1, b_m1, Abuf);
  {
    int nwg = (M_TOT / 128) * (HID / 128);   // 49*8 = 392
    gemm_mfma<128, 0><<<nwg, 256, 0, stream>>>(Abuf, wr1, hcl, K1, HID, HID / 128, nwg);
  }

  // ---- layer 2 (factorized: dense per-tap Y-GEMM + fused gather epilogue)
  {
    int nwg = (M_TOT / 128) * (NY / 128);    // 49*20 = 980
    gemm_mfma<128, 3><<<nwg, 256, 0, stream>>>(hcl, wy2, Y, HID, NY, NY / 128, nwg);
  }
  depi2_kernel<<<M_TOT / 4, 256, 0, stream>>>(Y, b_p2, b_m2, out);
}